// Round 12
// baseline (194.473 us; speedup 1.0000x reference)
//
#include <hip/hip_runtime.h>

#define N_ 4
#define L_ 1024
#define H_ 8
#define D_ 64

typedef _Float16 f16x8 __attribute__((ext_vector_type(8)));
typedef float f32x4 __attribute__((ext_vector_type(4)));

#define MFMA(A, B, C) __builtin_amdgcn_mfma_f32_16x16x32_f16(A, B, C, 0, 0, 0)

__device__ __forceinline__ ushort f2h(float x) {
    union { _Float16 h; ushort u; } c;
    c.h = (_Float16)x;
    return c.u;
}
__device__ __forceinline__ f16x8 ld8(const ushort* p) {
    return *(const f16x8*)p;
}
__device__ __forceinline__ f16x8 negf(f16x8 a) {
    uint4 u = __builtin_bit_cast(uint4, a);
    u.x ^= 0x80008000u; u.y ^= 0x80008000u; u.z ^= 0x80008000u; u.w ^= 0x80008000u;
    return __builtin_bit_cast(f16x8, u);
}
// load 8 consecutive f32, scale by s, convert to f16x8
__device__ __forceinline__ f16x8 cvt8s(const float* p, float s) {
    float4 a = *(const float4*)p;
    float4 b = *(const float4*)(p + 4);
    union { f16x8 v; _Float16 e[8]; } u;
    u.e[0] = (_Float16)(a.x * s); u.e[1] = (_Float16)(a.y * s);
    u.e[2] = (_Float16)(a.z * s); u.e[3] = (_Float16)(a.w * s);
    u.e[4] = (_Float16)(b.x * s); u.e[5] = (_Float16)(b.y * s);
    u.e[6] = (_Float16)(b.z * s); u.e[7] = (_Float16)(b.w * s);
    return u.v;
}
#define SCQ 0.18033688011112f   // (1/8)*log2(e)
__device__ __forceinline__ f16x8 cvt8(const float* p) { return cvt8s(p, SCQ); }

// async global -> LDS, 16B per lane, wave-uniform LDS base + lane*16
__device__ __forceinline__ void gl_lds16(const ushort* g, ushort* l) {
    __builtin_amdgcn_global_load_lds(
        (const __attribute__((address_space(1))) unsigned int*)g,
        (__attribute__((address_space(3))) unsigned int*)l, 16, 0, 0);
}

// ---- convert K: fp32 [n][l][h][d] -> f16 [aid][n][h][l][d], aid in {kr,ki}
__global__ void cvt_k(const float* __restrict__ k_r, const float* __restrict__ k_i,
                      ushort* __restrict__ dst) {
    int gid = blockIdx.x * 256 + threadIdx.x;   // 0..1048575 (x4 elems each)
    int aid = gid >> 19;
    int idx = (gid & 0x7FFFF) << 2;             // flat [n][h][l][d]
    int d  = idx & 63;
    int l  = (idx >> 6) & 1023;
    int hh = (idx >> 16) & 7;
    int n  = idx >> 19;
    const float* src = aid ? k_i : k_r;
    const float4 v = *(const float4*)(src + (((long)n * 1024 + l) * 8 + hh) * 64 + d);
    ushort4 o = make_ushort4(f2h(v.x), f2h(v.y), f2h(v.z), f2h(v.w));
    *(ushort4*)(dst + ((long)aid << 21) + idx) = o;
}

// ---- convert V: fp32 [n][s][h][d] -> f16 transposed [aid][n][h][d][s]
__global__ void cvt_v(const float* __restrict__ vr, const float* __restrict__ vi,
                      ushort* __restrict__ dst) {
    __shared__ ushort t[64][72];
    int bid = blockIdx.x;
    int aid = bid >> 9;
    int b   = bid & 511;
    int s0  = (b & 15) << 6;
    int hh  = (b >> 4) & 7;
    int n   = b >> 7;
    const float* src = aid ? vi : vr;
    int tid = threadIdx.x;
    int r  = tid >> 4;
    int cq = (tid & 15) << 2;
#pragma unroll
    for (int it = 0; it < 4; ++it) {
        int s = s0 + it * 16 + r;
        const float4 v = *(const float4*)(src + (((long)n * 1024 + s) * 8 + hh) * 64 + cq);
        t[it * 16 + r][cq + 0] = f2h(v.x);
        t[it * 16 + r][cq + 1] = f2h(v.y);
        t[it * 16 + r][cq + 2] = f2h(v.z);
        t[it * 16 + r][cq + 3] = f2h(v.w);
    }
    __syncthreads();
#pragma unroll
    for (int it = 0; it < 4; ++it) {
        int dd = it * 16 + r;
        ushort4 o;
        o.x = t[cq + 0][dd]; o.y = t[cq + 1][dd]; o.z = t[cq + 2][dd]; o.w = t[cq + 3][dd];
        *(ushort4*)(dst + ((long)aid << 21) + (((long)n * 8 + hh) * 64 + dd) * 1024 + s0 + cq) = o;
    }
}

#define BFLY(x)                                                             \
    x += __shfl_xor(x, 1); x += __shfl_xor(x, 2);                           \
    x += __shfl_xor(x, 4); x += __shfl_xor(x, 8);

// ws element layout (ushort): Kr @0, Ki @1<<21, Vr @2<<21, Vi @3<<21 (16 MB)
// rdbuf (float): byte offset 16 MB, 2*32768 floats.

// ---- flash-style single-pass attention for u + rd, s-split x2 ----
// grid 512 (XCD-swizzled -> (nh, l-tile64)), block 512 = 8 waves (same nh):
// wave = (sh s-half, lsub l-subtile-16). Each iteration stages BOTH halves'
// chunks (global_load_lds, both-sides XOR swizzle incl. (row>>2) term),
// double-buffered (LDS exactly 80KB -> 2 blocks/CU, 16 waves/CU).
// Epilogue: denom combine + normalized-partial exchange via dead wtl.
__launch_bounds__(512, 4)
__global__ void attn_u(const float* __restrict__ qr_g, const float* __restrict__ qi_g,
                       const ushort* __restrict__ ws, float* __restrict__ rdbuf,
                       float* __restrict__ out) {
    __shared__ ushort stgK[2][2][2][32][64];  // [buf][sh][part][s][d]   32KB
    __shared__ ushort stgV[2][2][2][64][32];  // [buf][sh][part][d][s]   32KB
    __shared__ ushort wtl[8][2][16][32];      // [wave][part][l][s]      16KB

    const int tid  = threadIdx.x;
    const int lane = tid & 63;
    const int wv   = tid >> 6;
    const int sh   = wv >> 2;       // s-half
    const int lsub = wv & 3;        // l-subtile
    const int col  = lane & 15;
    const int g    = lane >> 4;

    // XCD swizzle: XCD x serves nh in [4x,4x+4) -> 2MB K+V slice per L2
    const int id = blockIdx.x;
    const int x  = id & 7;
    const int j  = id >> 3;              // 0..63
    const int nh = x * 4 + (j >> 4);
    const int n  = nh >> 3;
    const int h  = nh & 7;
    const int l0 = (j & 15) * 64 + lsub * 16;

    const ushort* Kr = ws + ((long)nh << 16);                 // [1024][64]
    const ushort* Ki = ws + (1l << 21) + ((long)nh << 16);
    const ushort* Vr = ws + (2l << 21) + ((long)nh << 16);    // [64][1024]
    const ushort* Vi = ws + (3l << 21) + ((long)nh << 16);

    // Q fragments (row = col, k = g*8+e, +32), qn = -qi (all scaled SCQ)
    const long qg = (((long)n * 1024 + l0 + col) * 8 + h) * 64 + g * 8;
    const f16x8 qr0 = cvt8(qr_g + qg), qr1 = cvt8(qr_g + qg + 32);
    const f16x8 qi0 = cvt8(qi_g + qg), qi1 = cvt8(qi_g + qg + 32);
    const f16x8 qn0 = negf(qi0), qn1 = negf(qi1);

    // staging roles: wave stages its own sh; (part, half) from lsub
    const int kp  = lsub >> 1;                    // part staged
    const int hf  = lsub & 1;                     // row-half staged
    const int kbs = ((lane & 7) ^ (lane >> 3)) * 8;               // K src block
    const int vbs = (((lane & 3) ^ ((lane >> 2) & 3) ^ g) & 3) * 8; // V src block
    const ushort* Kst = kp ? Ki : Kr;
    const ushort* Vst = kp ? Vi : Vr;

    float dRs[4] = {0.f, 0.f, 0.f, 0.f};
    float dIs[4] = {0.f, 0.f, 0.f, 0.f};
    f32x4 uRR[4], uII[4], uRI[4], uIR[4];
#pragma unroll
    for (int db = 0; db < 4; ++db) {
        uRR[db] = (f32x4){0.f, 0.f, 0.f, 0.f};
        uII[db] = (f32x4){0.f, 0.f, 0.f, 0.f};
        uRI[db] = (f32x4){0.f, 0.f, 0.f, 0.f};
        uIR[db] = (f32x4){0.f, 0.f, 0.f, 0.f};
    }

    // read-side swizzled block offsets (lane-constant)
    const int kx  = (g ^ (col & 7)) * 8;                          // K: 8 blk/row
    const int kx2 = ((g + 4) ^ (col & 7)) * 8;
    const int vx  = ((g ^ (col & 3) ^ ((col >> 2) & 3)) & 3) * 8; // V & w: 4 blk

#define STAGE(buf, cc)                                                       \
    do {                                                                     \
        const int csh = sh * 16 + (cc);                                      \
        gl_lds16(Kst + (long)(csh * 32 + hf * 16 + (lane >> 3)) * 64 + kbs,  \
                 &stgK[buf][sh][kp][hf * 16][0]);                            \
        gl_lds16(Kst + (long)(csh * 32 + hf * 16 + 8 + (lane >> 3)) * 64 + kbs, \
                 &stgK[buf][sh][kp][hf * 16 + 8][0]);                        \
        gl_lds16(Vst + (long)(hf * 32 + (lane >> 2)) * 1024 + csh * 32 + vbs, \
                 &stgV[buf][sh][kp][hf * 32][0]);                            \
        gl_lds16(Vst + (long)(hf * 32 + 16 + (lane >> 2)) * 1024 + csh * 32 + vbs, \
                 &stgV[buf][sh][kp][hf * 32 + 16][0]);                       \
    } while (0)

    STAGE(0, 0);
    __syncthreads();

    for (int cc = 0; cc < 16; ++cc) {
        const int buf = cc & 1;
        if (cc < 15) STAGE(buf ^ 1, cc + 1);

        // ---- QK^T + exp2 -> w-tile (wave-private) ----
#pragma unroll
        for (int sb = 0; sb < 2; ++sb) {
            const int row = sb * 16 + col;
            f16x8 kr0 = ld8(&stgK[buf][sh][0][row][kx]);
            f16x8 kr1 = ld8(&stgK[buf][sh][0][row][kx2]);
            f16x8 ki0 = ld8(&stgK[buf][sh][1][row][kx]);
            f16x8 ki1 = ld8(&stgK[buf][sh][1][row][kx2]);
            f32x4 a0 = (f32x4){0.f, 0.f, 0.f, 0.f};
            a0 = MFMA(qr0, kr0, a0); a0 = MFMA(qr1, kr1, a0);
            a0 = MFMA(qn0, ki0, a0); a0 = MFMA(qn1, ki1, a0);
            f32x4 a1 = (f32x4){0.f, 0.f, 0.f, 0.f};
            a1 = MFMA(qr0, ki0, a1); a1 = MFMA(qr1, ki1, a1);
            a1 = MFMA(qi0, kr0, a1); a1 = MFMA(qi1, kr1, a1);
#pragma unroll
            for (int r = 0; r < 4; ++r) {
                const float wf = exp2f(a0[r]);
                const float vf = exp2f(a1[r]);
                dRs[r] += wf;
                dIs[r] += vf;
                const int l = 4 * g + r;
                const int scol = sb * 16 + col;
                const int pos = ((scol >> 3) ^ r ^ g) & 3;
                const int us = l * 32 + pos * 8 + (scol & 7);
                (&wtl[wv][0][0][0])[us] = f2h(wf);
                (&wtl[wv][1][0][0])[us] = f2h(vf);
            }
        }

        // ---- PV (k=32) ----
        f16x8 wr0 = ld8(&wtl[wv][0][col][vx]);
        f16x8 wi0 = ld8(&wtl[wv][1][col][vx]);
#pragma unroll
        for (int db = 0; db < 4; ++db) {
            const int row = db * 16 + col;
            f16x8 vr0 = ld8(&stgV[buf][sh][0][row][vx]);
            f16x8 vi0 = ld8(&stgV[buf][sh][1][row][vx]);
            uRR[db] = MFMA(wr0, vr0, uRR[db]);
            uII[db] = MFMA(wi0, vi0, uII[db]);
            uRI[db] = MFMA(wr0, vi0, uRI[db]);
            uIR[db] = MFMA(wi0, vr0, uIR[db]);
        }

        __syncthreads();   // staged buf^1 complete (vmcnt0) + all done with buf
    }

    BFLY(dRs[0]) BFLY(dRs[1]) BFLY(dRs[2]) BFLY(dRs[3])
    BFLY(dIs[0]) BFLY(dIs[1]) BFLY(dIs[2]) BFLY(dIs[3])

    // ---- combine denominators across s-halves (sst aliased into dead wtl)
    float* sstf = (float*)&wtl[0][0][0][0];   // [sh][lsub][part][16] = 1KB
    if (col == 0) {
#pragma unroll
        for (int r = 0; r < 4; ++r) {
            sstf[((sh * 4 + lsub) * 2 + 0) * 16 + 4 * g + r] = dRs[r];
            sstf[((sh * 4 + lsub) * 2 + 1) * 16 + 4 * g + r] = dIs[r];
        }
    }
    __syncthreads();

    float rdR[4], rdI[4];
#pragma unroll
    for (int r = 0; r < 4; ++r) {
        const int row = 4 * g + r;
        rdR[r] = 1.f / (sstf[(lsub * 2 + 0) * 16 + row] +
                        sstf[((4 + lsub) * 2 + 0) * 16 + row]);
        rdI[r] = 1.f / (sstf[(lsub * 2 + 1) * 16 + row] +
                        sstf[((4 + lsub) * 2 + 1) * 16 + row]);
    }

    if (sh == 0 && col == 0) {
#pragma unroll
        for (int r = 0; r < 4; ++r) {
            rdbuf[nh * 1024 + l0 + 4 * g + r] = rdR[r];
            rdbuf[32768 + nh * 1024 + l0 + 4 * g + r] = rdI[r];
        }
    }

    // normalized partials (rd common across halves -> normalize-then-add exact)
    f32x4 oR[4], oI[4];
#pragma unroll
    for (int db = 0; db < 4; ++db) {
#pragma unroll
        for (int r = 0; r < 4; ++r) {
            oR[db][r] = uRR[db][r] * rdR[r] - uII[db][r] * rdI[r];
            oI[db][r] = uRI[db][r] * rdR[r] + uIR[db][r] * rdI[r];
        }
    }
    __syncthreads();   // all sst reads done before cb clobbers wtl

    // ---- exchange partials via dead wtl (4KB per lsub, contiguous 16B/lane)
    float* cb = (float*)&wtl[lsub * 2][0][0][0];
    if (sh == 1) {
#pragma unroll
        for (int db = 0; db < 4; ++db) *(f32x4*)&cb[lane * 16 + db * 4] = oR[db];
    }
    __syncthreads();
    if (sh == 0) {
#pragma unroll
        for (int db = 0; db < 4; ++db) oR[db] += *(f32x4*)&cb[lane * 16 + db * 4];
    }
    __syncthreads();
    if (sh == 1) {
#pragma unroll
        for (int db = 0; db < 4; ++db) *(f32x4*)&cb[lane * 16 + db * 4] = oI[db];
    }
    __syncthreads();

    if (sh == 0) {
        const long OFF_UI = 2097152;
#pragma unroll
        for (int db = 0; db < 4; ++db) {
            f32x4 oid = oI[db] + *(f32x4*)&cb[lane * 16 + db * 4];
#pragma unroll
            for (int r = 0; r < 4; ++r) {
                const int l = l0 + 4 * g + r;
                const int d = db * 16 + col;
                const long base = (((long)n * L_ + l) * H_ + h) * D_ + d;
                out[base] = oR[db][r];
                out[OFF_UI + base] = oid[r];
            }
        }
    }
#undef STAGE
}

// ---- a = 0.125 * sum_h exp2(arg_h) * rd_h ---- LDS-staged K recompute
// grid 1024 (XCD-swizzled -> (n, l-tile64, s-chunk64)), block 256 = 4 waves,
// wave owns 16 l-rows x full 64-s chunk. h-loop with double-buffered LDS K
// staging (global_load_lds, both-sides XOR swizzle), in-register h-sum.
__launch_bounds__(256, 4)
__global__ void kern_a(const float* __restrict__ qr_g, const float* __restrict__ qi_g,
                       const ushort* __restrict__ ws, const float* __restrict__ rdbuf,
                       float* __restrict__ out) {
    __shared__ ushort stgK[2][2][64][64];   // [buf][part][s][d]  32KB
    __shared__ float lrd[8][2][64];         // [h][part][row]      4KB

    const int tid  = threadIdx.x;
    const int lane = tid & 63;
    const int wv   = tid >> 6;
    const int col  = lane & 15;
    const int g    = lane >> 4;

    // XCD swizzle: id&7 = XCD x; n = x>>1 -> K(n)=4MB resident per L2 pair
    const int id  = blockIdx.x;
    const int x   = id & 7;
    const int q   = id >> 3;             // 0..127
    const int n   = x >> 1;
    const int idx = (x & 1) * 128 + q;   // 0..255 within n
    const int lt0 = (idx >> 4) * 64;     // l-tile base
    const int sc  = idx & 15;            // s-chunk (64 cols)
    const int l0  = lt0 + wv * 16;       // wave's row base

    const ushort* KrB = ws + ((long)(n * 8) << 16);             // head 0
    const ushort* KiB = ws + (1l << 21) + ((long)(n * 8) << 16);

    // preload rd for all 8 heads x 64 rows
#pragma unroll
    for (int i = 0; i < 4; ++i) {
        const int t = i * 256 + tid;
        (&lrd[0][0][0])[t] =
            rdbuf[((t >> 6) & 1) * 32768 + (n * 8 + (t >> 7)) * 1024 + lt0 + (t & 63)];
    }

    // staging roles: wave stages part sp, rows (wv&1)*32 .. +32
    const int sp   = wv >> 1;
    const int kbs  = ((lane & 7) ^ (lane >> 3)) * 8;   // pre-swizzled src block

#define STAGEA(buf, hh)                                                      \
    do {                                                                     \
        const ushort* Kp = (sp ? KiB : KrB) + ((long)(hh) << 16);            \
        _Pragma("unroll")                                                    \
        for (int i = 0; i < 4; ++i) {                                        \
            const int krow = (wv & 1) * 32 + i * 8 + (lane >> 3);            \
            gl_lds16(Kp + (long)(sc * 64 + krow) * 64 + kbs,                 \
                     &stgK[buf][sp][(wv & 1) * 32 + i * 8][0]);              \
        }                                                                    \
    } while (0)

    f32x4 aR[4], aI[4];
#pragma unroll
    for (int i = 0; i < 4; ++i) {
        aR[i] = (f32x4){0.f, 0.f, 0.f, 0.f};
        aI[i] = (f32x4){0.f, 0.f, 0.f, 0.f};
    }

    const int kx  = (g ^ (col & 7)) * 8;
    const int kx2 = ((g + 4) ^ (col & 7)) * 8;

    STAGEA(0, 0);
    __syncthreads();

    for (int h = 0; h < 8; ++h) {
        const int buf = h & 1;
        if (h < 7) STAGEA(buf ^ 1, h + 1);

        // Q fragments for this head (row = col of wave's 16, k = g*8+e)
        const long qg = (((long)n * 1024 + l0 + col) * 8 + h) * 64 + g * 8;
        const f16x8 qr0 = cvt8(qr_g + qg), qr1 = cvt8(qr_g + qg + 32);
        const f16x8 qi0 = cvt8(qi_g + qg), qi1 = cvt8(qi_g + qg + 32);
        const f16x8 qn0 = negf(qi0), qn1 = negf(qi1);

        float rdR[4], rdI[4];
#pragma unroll
        for (int r = 0; r < 4; ++r) {
            rdR[r] = lrd[h][0][wv * 16 + 4 * g + r];
            rdI[r] = lrd[h][1][wv * 16 + 4 * g + r];
        }

#pragma unroll
        for (int sb = 0; sb < 4; ++sb) {
            const int row = sb * 16 + col;
            f16x8 kr0 = ld8(&stgK[buf][0][row][kx]);
            f16x8 kr1 = ld8(&stgK[buf][0][row][kx2]);
            f16x8 ki0 = ld8(&stgK[buf][1][row][kx]);
            f16x8 ki1 = ld8(&stgK[buf][1][row][kx2]);
            f32x4 a0 = (f32x4){0.f, 0.f, 0.f, 0.f};
            a0 = MFMA(qr0, kr0, a0); a0 = MFMA(qr1, kr1, a0);
            a0 = MFMA(qn0, ki0, a0); a0 = MFMA(qn1, ki1, a0);
            f32x4 a1 = (f32x4){0.f, 0.f, 0.f, 0.f};
            a1 = MFMA(qr0, ki0, a1); a1 = MFMA(qr1, ki1, a1);
            a1 = MFMA(qi0, kr0, a1); a1 = MFMA(qi1, kr1, a1);
#pragma unroll
            for (int r = 0; r < 4; ++r) {
                aR[sb][r] += exp2f(a0[r]) * rdR[r];
                aI[sb][r] += exp2f(a1[r]) * rdI[r];
            }
        }
        __syncthreads();
    }

    const long OFF_AR = 4194304;
    const long OFF_AI = 8388608;
#pragma unroll
    for (int sb = 0; sb < 4; ++sb) {
#pragma unroll
        for (int r = 0; r < 4; ++r) {
            const int l = l0 + 4 * g + r;
            const int s = sc * 64 + sb * 16 + col;
            const long ab = ((long)n * 1024 + l) * 1024 + s;
            out[OFF_AR + ab] = aR[sb][r] * 0.125f;
            out[OFF_AI + ab] = aI[sb][r] * 0.125f;
        }
    }
#undef STAGEA
}

extern "C" void kernel_launch(void* const* d_in, const int* in_sizes, int n_in,
                              void* d_out, int out_size, void* d_ws, size_t ws_size,
                              hipStream_t stream) {
    const float* qr = (const float*)d_in[0];
    const float* qi = (const float*)d_in[1];
    const float* kr = (const float*)d_in[2];
    const float* ki = (const float*)d_in[3];
    const float* vr = (const float*)d_in[4];
    const float* vi = (const float*)d_in[5];
    ushort* ws = (ushort*)d_ws;                              // 16 MB f16 K/V
    float* rdbuf = (float*)((char*)d_ws + (16ull << 20));    // 256 KB @ 16 MB
    float* out = (float*)d_out;

    hipLaunchKernelGGL(cvt_k, dim3(4096), dim3(256), 0, stream, kr, ki, ws);
    hipLaunchKernelGGL(cvt_v, dim3(1024), dim3(256), 0, stream, vr, vi, ws + (2l << 21));
    hipLaunchKernelGGL(attn_u, dim3(512), dim3(512), 0, stream, qr, qi, ws, rdbuf, out);
    hipLaunchKernelGGL(kern_a, dim3(1024), dim3(256), 0, stream, qr, qi, ws, rdbuf, out);
}

// Round 13
// 116.527 us; speedup vs baseline: 1.6689x; 1.6689x over previous
//
#include <hip/hip_runtime.h>

#define N_ 4
#define L_ 1024
#define H_ 8
#define D_ 64

typedef _Float16 f16x8 __attribute__((ext_vector_type(8)));
typedef float f32x4 __attribute__((ext_vector_type(4)));

#define MFMA(A, B, C) __builtin_amdgcn_mfma_f32_16x16x32_f16(A, B, C, 0, 0, 0)

__device__ __forceinline__ ushort f2h(float x) {
    union { _Float16 h; ushort u; } c;
    c.h = (_Float16)x;
    return c.u;
}
__device__ __forceinline__ f16x8 ld8(const ushort* p) {
    return *(const f16x8*)p;
}
__device__ __forceinline__ f16x8 negf(f16x8 a) {
    uint4 u = __builtin_bit_cast(uint4, a);
    u.x ^= 0x80008000u; u.y ^= 0x80008000u; u.z ^= 0x80008000u; u.w ^= 0x80008000u;
    return __builtin_bit_cast(f16x8, u);
}
// load 8 consecutive f32, scale by s, convert to f16x8
__device__ __forceinline__ f16x8 cvt8s(const float* p, float s) {
    float4 a = *(const float4*)p;
    float4 b = *(const float4*)(p + 4);
    union { f16x8 v; _Float16 e[8]; } u;
    u.e[0] = (_Float16)(a.x * s); u.e[1] = (_Float16)(a.y * s);
    u.e[2] = (_Float16)(a.z * s); u.e[3] = (_Float16)(a.w * s);
    u.e[4] = (_Float16)(b.x * s); u.e[5] = (_Float16)(b.y * s);
    u.e[6] = (_Float16)(b.z * s); u.e[7] = (_Float16)(b.w * s);
    return u.v;
}
#define SCQ 0.18033688011112f   // (1/8)*log2(e)
__device__ __forceinline__ f16x8 cvt8(const float* p) { return cvt8s(p, SCQ); }

// async global -> LDS, 16B per lane, wave-uniform LDS base + lane*16
__device__ __forceinline__ void gl_lds16(const ushort* g, ushort* l) {
    __builtin_amdgcn_global_load_lds(
        (const __attribute__((address_space(1))) unsigned int*)g,
        (__attribute__((address_space(3))) unsigned int*)l, 16, 0, 0);
}

// ---- convert K: fp32 [n][l][h][d] -> f16 [aid][n][h][l][d], aid in {kr,ki}
__global__ void cvt_k(const float* __restrict__ k_r, const float* __restrict__ k_i,
                      ushort* __restrict__ dst) {
    int gid = blockIdx.x * 256 + threadIdx.x;   // 0..1048575 (x4 elems each)
    int aid = gid >> 19;
    int idx = (gid & 0x7FFFF) << 2;             // flat [n][h][l][d]
    int d  = idx & 63;
    int l  = (idx >> 6) & 1023;
    int hh = (idx >> 16) & 7;
    int n  = idx >> 19;
    const float* src = aid ? k_i : k_r;
    const float4 v = *(const float4*)(src + (((long)n * 1024 + l) * 8 + hh) * 64 + d);
    ushort4 o = make_ushort4(f2h(v.x), f2h(v.y), f2h(v.z), f2h(v.w));
    *(ushort4*)(dst + ((long)aid << 21) + idx) = o;
}

// ---- convert V: fp32 [n][s][h][d] -> f16 transposed [aid][n][h][d][s]
__global__ void cvt_v(const float* __restrict__ vr, const float* __restrict__ vi,
                      ushort* __restrict__ dst) {
    __shared__ ushort t[64][72];
    int bid = blockIdx.x;
    int aid = bid >> 9;
    int b   = bid & 511;
    int s0  = (b & 15) << 6;
    int hh  = (b >> 4) & 7;
    int n   = b >> 7;
    const float* src = aid ? vi : vr;
    int tid = threadIdx.x;
    int r  = tid >> 4;
    int cq = (tid & 15) << 2;
#pragma unroll
    for (int it = 0; it < 4; ++it) {
        int s = s0 + it * 16 + r;
        const float4 v = *(const float4*)(src + (((long)n * 1024 + s) * 8 + hh) * 64 + cq);
        t[it * 16 + r][cq + 0] = f2h(v.x);
        t[it * 16 + r][cq + 1] = f2h(v.y);
        t[it * 16 + r][cq + 2] = f2h(v.z);
        t[it * 16 + r][cq + 3] = f2h(v.w);
    }
    __syncthreads();
#pragma unroll
    for (int it = 0; it < 4; ++it) {
        int dd = it * 16 + r;
        ushort4 o;
        o.x = t[cq + 0][dd]; o.y = t[cq + 1][dd]; o.z = t[cq + 2][dd]; o.w = t[cq + 3][dd];
        *(ushort4*)(dst + ((long)aid << 21) + (((long)n * 8 + hh) * 64 + dd) * 1024 + s0 + cq) = o;
    }
}

#define BFLY(x)                                                             \
    x += __shfl_xor(x, 1); x += __shfl_xor(x, 2);                           \
    x += __shfl_xor(x, 4); x += __shfl_xor(x, 8);

// ws element layout (ushort): Kr @0, Ki @1<<21, Vr @2<<21, Vi @3<<21 (16 MB)
// rdbuf (float): byte offset 16 MB; [0,32768) = rdR (p=0), [32768,65536) = rdI.

// ---- flash-style single-pass attention for u + rd, PARITY-SPLIT waves ----
// grid 512 (XCD-swizzled -> (nh, l-tile64)), block 512 = 8 waves (same nh):
// wave = (p parity, lsub). Each wave: 16 rows x full 1024 s, ONE parity arg:
//   p=0: w = exp2(qr.kr - qi.ki), d_R, uA = w.Vr, uB = w.Vi
//   p=1: w = exp2(qr.ki + qi.kr), d_I, uA, uB likewise.
// K/V staged to LDS (global_load_lds, both-sides XOR swizzle), double-buffered.
// acc = 32 AGPR -> total regs ~96 < 128 -> 4 waves/SIMD, 16 waves/CU.
// Epilogue: u_real = uA0*rdR - uB1*rdI ; u_imag = uB0*rdR + uA1*rdI,
// exchanged via dead stgK region.
__launch_bounds__(512, 4)
__global__ void attn_u(const float* __restrict__ qr_g, const float* __restrict__ qi_g,
                       const ushort* __restrict__ ws, float* __restrict__ rdbuf,
                       float* __restrict__ out) {
    __shared__ ushort stgK[2][2][32][64];   // [buf][part][s][d]  16KB
    __shared__ ushort stgV[2][2][64][32];   // [buf][part][d][s]  16KB
    __shared__ ushort wtl[8][16][32];       // [wave][l][s]        8KB

    const int tid  = threadIdx.x;
    const int lane = tid & 63;
    const int wv   = tid >> 6;
    const int p    = wv >> 2;       // parity
    const int lsub = wv & 3;        // l-subtile
    const int col  = lane & 15;
    const int g    = lane >> 4;

    // XCD swizzle: XCD x serves nh in [4x,4x+4) -> 2MB K+V slice per L2
    const int id = blockIdx.x;
    const int x  = id & 7;
    const int j  = id >> 3;              // 0..63
    const int nh = x * 4 + (j >> 4);
    const int n  = nh >> 3;
    const int h  = nh & 7;
    const int l0 = (j & 15) * 64 + lsub * 16;

    const ushort* Kr = ws + ((long)nh << 16);                 // [1024][64]
    const ushort* Ki = ws + (1l << 21) + ((long)nh << 16);
    const ushort* Vr = ws + (2l << 21) + ((long)nh << 16);    // [64][1024]
    const ushort* Vi = ws + (3l << 21) + ((long)nh << 16);

    // Q fragments (row = col, k = g*8+e, +32); qx pre-signed: -qi for p=0
    const long qg = (((long)n * 1024 + l0 + col) * 8 + h) * 64 + g * 8;
    const float sgn = p ? SCQ : -SCQ;
    const f16x8 qr0 = cvt8(qr_g + qg), qr1 = cvt8(qr_g + qg + 32);
    const f16x8 qx0 = cvt8s(qi_g + qg, sgn), qx1 = cvt8s(qi_g + qg + 32, sgn);

    // staging roles: wave stages part p; rows by lsub. 1 K + 1 V call/thread.
    const int krow = lsub * 8 + (lane >> 3);     // K row (of 32), 8 lanes/row
    const int kbs  = ((lane & 7) ^ (krow & 7)) * 8;
    const int vrow = lsub * 16 + (lane >> 2);    // V row (of 64), 4 lanes/row
    const int vbs  = ((lane & 3) ^ (vrow & 3)) * 8;
    const ushort* Kst = p ? Ki : Kr;
    const ushort* Vst = p ? Vi : Vr;

    float ds[4] = {0.f, 0.f, 0.f, 0.f};
    f32x4 uA[4], uB[4];
#pragma unroll
    for (int db = 0; db < 4; ++db) {
        uA[db] = (f32x4){0.f, 0.f, 0.f, 0.f};
        uB[db] = (f32x4){0.f, 0.f, 0.f, 0.f};
    }

    // read-side swizzled block offsets (lane-constant)
    const int kx  = (g ^ (col & 7)) * 8;         // K: 8 blk/row
    const int kx2 = ((g + 4) ^ (col & 7)) * 8;
    const int vx  = (g ^ (col & 3)) * 8;         // V & w: 4 blk/row

#define STAGE(buf, cc)                                                       \
    do {                                                                     \
        gl_lds16(Kst + (long)((cc) * 32 + krow) * 64 + kbs,                  \
                 &stgK[buf][p][lsub * 8][0]);                                \
        gl_lds16(Vst + (long)vrow * 1024 + (cc) * 32 + vbs,                  \
                 &stgV[buf][p][lsub * 16][0]);                               \
    } while (0)

    STAGE(0, 0);
    __syncthreads();

    for (int cc = 0; cc < 32; ++cc) {
        const int buf = cc & 1;
        if (cc < 31) STAGE(buf ^ 1, cc + 1);

        // ---- one-parity QK^T + exp2 -> w-tile (wave-private) ----
#pragma unroll
        for (int sb = 0; sb < 2; ++sb) {
            const int row = sb * 16 + col;
            f16x8 ka0 = ld8(&stgK[buf][p][row][kx]);
            f16x8 ka1 = ld8(&stgK[buf][p][row][kx2]);
            f16x8 kb0 = ld8(&stgK[buf][p ^ 1][row][kx]);
            f16x8 kb1 = ld8(&stgK[buf][p ^ 1][row][kx2]);
            f32x4 a0 = (f32x4){0.f, 0.f, 0.f, 0.f};
            a0 = MFMA(qr0, ka0, a0); a0 = MFMA(qr1, ka1, a0);
            a0 = MFMA(qx0, kb0, a0); a0 = MFMA(qx1, kb1, a0);
#pragma unroll
            for (int r = 0; r < 4; ++r) {
                const float wf = exp2f(a0[r]);
                ds[r] += wf;
                const int l = 4 * g + r;
                const int scol = sb * 16 + col;
                const int us = l * 32 + (((scol >> 3) ^ (l & 3)) << 3) + (scol & 7);
                (&wtl[wv][0][0])[us] = f2h(wf);
            }
        }

        // ---- PV (k=32): uA += w.Vr, uB += w.Vi ----
        f16x8 w0 = ld8(&wtl[wv][col][vx]);
#pragma unroll
        for (int db = 0; db < 4; ++db) {
            const int row = db * 16 + col;
            f16x8 vr0 = ld8(&stgV[buf][0][row][vx]);
            f16x8 vi0 = ld8(&stgV[buf][1][row][vx]);
            uA[db] = MFMA(w0, vr0, uA[db]);
            uB[db] = MFMA(w0, vi0, uB[db]);
        }

        __syncthreads();   // staged buf^1 complete (vmcnt0) + all done with buf
    }

    BFLY(ds[0]) BFLY(ds[1]) BFLY(ds[2]) BFLY(ds[3])

    float rd[4];
#pragma unroll
    for (int r = 0; r < 4; ++r) rd[r] = 1.f / ds[r];

    if (col == 0) {
#pragma unroll
        for (int r = 0; r < 4; ++r)
            rdbuf[p * 32768 + nh * 1024 + l0 + 4 * g + r] = rd[r];
    }

    // normalized partials
#pragma unroll
    for (int db = 0; db < 4; ++db) {
#pragma unroll
        for (int r = 0; r < 4; ++r) {
            uA[db][r] *= rd[r];
            uB[db][r] *= rd[r];
        }
    }

    // ---- exchange via dead stgK (16KB): [lsub][lane][16 f32] contiguous ----
    float* cb = (float*)&stgK[0][0][0][0];
    const int ci = (lsub * 64 + lane) * 16;
    if (p == 1) {
#pragma unroll
        for (int db = 0; db < 4; ++db) *(f32x4*)&cb[ci + db * 4] = uB[db];
    }
    __syncthreads();
    f32x4 oR[4];
    if (p == 0) {
#pragma unroll
        for (int db = 0; db < 4; ++db) oR[db] = uA[db] - *(f32x4*)&cb[ci + db * 4];
    }
    __syncthreads();
    if (p == 1) {
#pragma unroll
        for (int db = 0; db < 4; ++db) *(f32x4*)&cb[ci + db * 4] = uA[db];
    }
    __syncthreads();

    if (p == 0) {
        const long OFF_UI = 2097152;
#pragma unroll
        for (int db = 0; db < 4; ++db) {
            f32x4 oI = uB[db] + *(f32x4*)&cb[ci + db * 4];
#pragma unroll
            for (int r = 0; r < 4; ++r) {
                const int l = l0 + 4 * g + r;
                const int d = db * 16 + col;
                const long base = (((long)n * L_ + l) * H_ + h) * D_ + d;
                out[base] = oR[db][r];
                out[OFF_UI + base] = oI[r];
            }
        }
    }
#undef STAGE
}

// ---- a = 0.125 * sum_h exp2(arg_h) * rd_h ---- LDS-staged K recompute
// grid 1024 (XCD-swizzled -> (n, l-tile64, s-chunk64)), block 256 = 4 waves,
// wave owns 16 l-rows x full 64-s chunk. h-loop with double-buffered LDS K
// staging (global_load_lds, both-sides XOR swizzle), in-register h-sum.
__launch_bounds__(256, 4)
__global__ void kern_a(const float* __restrict__ qr_g, const float* __restrict__ qi_g,
                       const ushort* __restrict__ ws, const float* __restrict__ rdbuf,
                       float* __restrict__ out) {
    __shared__ ushort stgK[2][2][64][64];   // [buf][part][s][d]  32KB
    __shared__ float lrd[8][2][64];         // [h][part][row]      4KB

    const int tid  = threadIdx.x;
    const int lane = tid & 63;
    const int wv   = tid >> 6;
    const int col  = lane & 15;
    const int g    = lane >> 4;

    // XCD swizzle: id&7 = XCD x; n = x>>1 -> K(n)=4MB resident per L2 pair
    const int id  = blockIdx.x;
    const int x   = id & 7;
    const int q   = id >> 3;             // 0..127
    const int n   = x >> 1;
    const int idx = (x & 1) * 128 + q;   // 0..255 within n
    const int lt0 = (idx >> 4) * 64;     // l-tile base
    const int sc  = idx & 15;            // s-chunk (64 cols)
    const int l0  = lt0 + wv * 16;       // wave's row base

    const ushort* KrB = ws + ((long)(n * 8) << 16);             // head 0
    const ushort* KiB = ws + (1l << 21) + ((long)(n * 8) << 16);

    // preload rd for all 8 heads x 64 rows
#pragma unroll
    for (int i = 0; i < 4; ++i) {
        const int t = i * 256 + tid;
        (&lrd[0][0][0])[t] =
            rdbuf[((t >> 6) & 1) * 32768 + (n * 8 + (t >> 7)) * 1024 + lt0 + (t & 63)];
    }

    // staging roles: wave stages part sp, rows (wv&1)*32 .. +32
    const int sp   = wv >> 1;
    const int kbs  = ((lane & 7) ^ (lane >> 3)) * 8;   // pre-swizzled src block

#define STAGEA(buf, hh)                                                      \
    do {                                                                     \
        const ushort* Kp = (sp ? KiB : KrB) + ((long)(hh) << 16);            \
        _Pragma("unroll")                                                    \
        for (int i = 0; i < 4; ++i) {                                        \
            const int krow = (wv & 1) * 32 + i * 8 + (lane >> 3);            \
            gl_lds16(Kp + (long)(sc * 64 + krow) * 64 + kbs,                 \
                     &stgK[buf][sp][(wv & 1) * 32 + i * 8][0]);              \
        }                                                                    \
    } while (0)

    f32x4 aR[4], aI[4];
#pragma unroll
    for (int i = 0; i < 4; ++i) {
        aR[i] = (f32x4){0.f, 0.f, 0.f, 0.f};
        aI[i] = (f32x4){0.f, 0.f, 0.f, 0.f};
    }

    const int kx  = (g ^ (col & 7)) * 8;
    const int kx2 = ((g + 4) ^ (col & 7)) * 8;

    STAGEA(0, 0);
    __syncthreads();

    for (int h = 0; h < 8; ++h) {
        const int buf = h & 1;
        if (h < 7) STAGEA(buf ^ 1, h + 1);

        // Q fragments for this head (row = col of wave's 16, k = g*8+e)
        const long qg = (((long)n * 1024 + l0 + col) * 8 + h) * 64 + g * 8;
        const f16x8 qr0 = cvt8(qr_g + qg), qr1 = cvt8(qr_g + qg + 32);
        const f16x8 qi0 = cvt8(qi_g + qg), qi1 = cvt8(qi_g + qg + 32);
        const f16x8 qn0 = negf(qi0), qn1 = negf(qi1);

        float rdR[4], rdI[4];
#pragma unroll
        for (int r = 0; r < 4; ++r) {
            rdR[r] = lrd[h][0][wv * 16 + 4 * g + r];
            rdI[r] = lrd[h][1][wv * 16 + 4 * g + r];
        }

#pragma unroll
        for (int sb = 0; sb < 4; ++sb) {
            const int row = sb * 16 + col;
            f16x8 kr0 = ld8(&stgK[buf][0][row][kx]);
            f16x8 kr1 = ld8(&stgK[buf][0][row][kx2]);
            f16x8 ki0 = ld8(&stgK[buf][1][row][kx]);
            f16x8 ki1 = ld8(&stgK[buf][1][row][kx2]);
            f32x4 a0 = (f32x4){0.f, 0.f, 0.f, 0.f};
            a0 = MFMA(qr0, kr0, a0); a0 = MFMA(qr1, kr1, a0);
            a0 = MFMA(qn0, ki0, a0); a0 = MFMA(qn1, ki1, a0);
            f32x4 a1 = (f32x4){0.f, 0.f, 0.f, 0.f};
            a1 = MFMA(qr0, ki0, a1); a1 = MFMA(qr1, ki1, a1);
            a1 = MFMA(qi0, kr0, a1); a1 = MFMA(qi1, kr1, a1);
#pragma unroll
            for (int r = 0; r < 4; ++r) {
                aR[sb][r] += exp2f(a0[r]) * rdR[r];
                aI[sb][r] += exp2f(a1[r]) * rdI[r];
            }
        }
        __syncthreads();
    }

    const long OFF_AR = 4194304;
    const long OFF_AI = 8388608;
#pragma unroll
    for (int sb = 0; sb < 4; ++sb) {
#pragma unroll
        for (int r = 0; r < 4; ++r) {
            const int l = l0 + 4 * g + r;
            const int s = sc * 64 + sb * 16 + col;
            const long ab = ((long)n * 1024 + l) * 1024 + s;
            out[OFF_AR + ab] = aR[sb][r] * 0.125f;
            out[OFF_AI + ab] = aI[sb][r] * 0.125f;
        }
    }
#undef STAGEA
}

extern "C" void kernel_launch(void* const* d_in, const int* in_sizes, int n_in,
                              void* d_out, int out_size, void* d_ws, size_t ws_size,
                              hipStream_t stream) {
    const float* qr = (const float*)d_in[0];
    const float* qi = (const float*)d_in[1];
    const float* kr = (const float*)d_in[2];
    const float* ki = (const float*)d_in[3];
    const float* vr = (const float*)d_in[4];
    const float* vi = (const float*)d_in[5];
    ushort* ws = (ushort*)d_ws;                              // 16 MB f16 K/V
    float* rdbuf = (float*)((char*)d_ws + (16ull << 20));    // 256 KB @ 16 MB
    float* out = (float*)d_out;

    hipLaunchKernelGGL(cvt_k, dim3(4096), dim3(256), 0, stream, kr, ki, ws);
    hipLaunchKernelGGL(cvt_v, dim3(1024), dim3(256), 0, stream, vr, vi, ws + (2l << 21));
    hipLaunchKernelGGL(attn_u, dim3(512), dim3(512), 0, stream, qr, qi, ws, rdbuf, out);
    hipLaunchKernelGGL(kern_a, dim3(1024), dim3(256), 0, stream, qr, qi, ws, rdbuf, out);
}